// Round 9
// baseline (1561.775 us; speedup 1.0000x reference)
//
#include <hip/hip_runtime.h>
#include <hip/hip_bf16.h>
#include <stdint.h>

#define B_Q   1024
#define C_K   262144
#define D_DIM 512
#define V_DIM 512
#define K_TOP 8
#define BM 256
#define BN 256
#define BK 64
#define NT (C_K/BN)    /* 1024 n-tiles */
#define MT (B_Q/BM)    /* 4 m-tiles */
#define NKT (D_DIM/BK) /* 8 K-tiles per nt-tile */
#define TPB 8          /* nt-tiles per persistent block (2 blocks/CU) */
#define CAP 2048       /* candidate list capacity per query (E[n]~293) */
#define QS 8.0f        /* per-side fp8 pre-scale */
#define TAU_S 8.64f    /* 64 * 0.135 (z=3.05); rescore window 64 -> 13-sigma margin */
#define RWIN 64        /* exact-rescore window */

typedef float f32x4 __attribute__((ext_vector_type(4)));
typedef __attribute__((address_space(3))) unsigned char lds_uchar;
typedef __attribute__((address_space(1))) const unsigned char gbl_uchar;

// One wave per row: L2-normalize (fp32 norm), scale by QS, emit fp8 e4m3.
// Block 0 additionally zeroes the candidate counters (when cnt != nullptr).
__global__ __launch_bounds__(256) void nrm_rows(const float* __restrict__ in,
                                                uint8_t* __restrict__ out,
                                                int nrows, int* cnt, int ncnt){
  if (cnt != nullptr && blockIdx.x == 0){
    for (int i = threadIdx.x; i < ncnt; i += 256) cnt[i] = 0;
  }
  int row  = blockIdx.x*4 + (threadIdx.x>>6);
  int lane = threadIdx.x & 63;
  if (row >= nrows) return;
  const float4* r4 = (const float4*)(in + (size_t)row*D_DIM);
  float4 a = r4[lane*2], b = r4[lane*2+1];
  float ss = a.x*a.x+a.y*a.y+a.z*a.z+a.w*a.w
           + b.x*b.x+b.y*b.y+b.z*b.z+b.w*b.w;
  #pragma unroll
  for (int off=32; off>0; off>>=1) ss += __shfl_xor(ss, off);
  float rn = QS / fmaxf(sqrtf(ss), 1e-12f);
  int w0 = __builtin_amdgcn_cvt_pk_fp8_f32(a.x*rn, a.y*rn, 0,  false);
  w0     = __builtin_amdgcn_cvt_pk_fp8_f32(a.z*rn, a.w*rn, w0, true);
  int w1 = __builtin_amdgcn_cvt_pk_fp8_f32(b.x*rn, b.y*rn, 0,  false);
  w1     = __builtin_amdgcn_cvt_pk_fp8_f32(b.z*rn, b.w*rn, w1, true);
  ((uint2*)(out + (size_t)row*D_DIM))[lane] = make_uint2((unsigned)w0, (unsigned)w1);
}

// PERSISTENT 256x256 fp8 MFMA GEMM (scores scaled by 64): grid=512 (2
// blocks/CU — 64KB LDS each, cross-block TLP covers barrier/latency stalls),
// each block owns one mt and walks 8 nt-tiles; counted vmcnt(4) K-tile
// prefetch flows across tile boundaries. LDS 2 x 32KB double buffer.
// Swizzle: 16B unit u' = u ^ ((row>>1)&3) — with the natural row&1 address
// bit, 8 consecutive rows hit 8 distinct 16B bank regions (only free 2-way
// r/r+8 aliasing remains). Linear LDS dest + inverse-swizzled global source
// (global_load_lds-compatible). Fragments via ds_read_b64.
// Epilogue per nt-tile = threshold filter + rare atomic append.
__global__ __launch_bounds__(512, 4) void gemm_topk(const uint8_t* __restrict__ qn,
                                                    const uint8_t* __restrict__ kn,
                                                    int* __restrict__ cnt,
                                                    float2* __restrict__ cand){
  extern __shared__ __align__(16) unsigned char smem[];   // 65536 bytes

  const int tid  = threadIdx.x;
  const int lane = tid & 63;
  const int w    = tid >> 6;           // 0..7
  const int wm = w >> 2, wn = w & 3;   // 2 x 4 wave grid

  const unsigned bid = blockIdx.x;     // 0..511
  const int xcd  = bid & 7;
  const int s    = bid >> 3;           // 0..63
  const int mt   = s & 3;
  const int nt0  = xcd*128 + (s >> 2); // tile tt -> nt = nt0 + 16*tt

  f32x4 zero4 = {0.f,0.f,0.f,0.f};
  f32x4 acc[8][4];
  #pragma unroll
  for (int a=0;a<8;a++)
    #pragma unroll
    for (int b=0;b<4;b++) acc[a][b] = zero4;

  const uint8_t* ab  = qn + (size_t)mt*BM*D_DIM;
  const uint8_t* bb0 = kn + (size_t)nt0*BN*D_DIM;

  // staging map: thread t covers 16B units {t, t+512} of A and of B.
  // unit n -> row n>>2, dest-unit n&3; source unit = (n&3) ^ ((row>>1)&3).
  const int srow = tid >> 2;                                  // 0..127
  const unsigned ssw = (unsigned)(((tid & 3) ^ ((srow >> 1) & 3)) << 4);
  const uint8_t* aptr = ab  + (size_t)srow*D_DIM + ssw;       // += 64/K-tile
  const uint8_t* bptr = bb0 + (size_t)srow*D_DIM + ssw;
  const unsigned dst0 = (unsigned)tid*16u;

  #define STAGE_KT(buf_) do{                                                    \
    const unsigned cb_ = (unsigned)(buf_)*32768u;                                \
    __builtin_amdgcn_global_load_lds((gbl_uchar*)(aptr),                         \
        (lds_uchar*)(smem + cb_ + dst0), 16, 0, 0);                              \
    __builtin_amdgcn_global_load_lds((gbl_uchar*)(aptr + 128*D_DIM),             \
        (lds_uchar*)(smem + cb_ + 8192u + dst0), 16, 0, 0);                      \
    __builtin_amdgcn_global_load_lds((gbl_uchar*)(bptr),                         \
        (lds_uchar*)(smem + cb_ + 16384u + dst0), 16, 0, 0);                     \
    __builtin_amdgcn_global_load_lds((gbl_uchar*)(bptr + 128*D_DIM),             \
        (lds_uchar*)(smem + cb_ + 24576u + dst0), 16, 0, 0);                     \
  }while(0)

  // frag byte offset for (row_, slot s_): s_ = ks*4 + (lane>>4), 8B granule
  #define FOFF(row_, s_) \
    ((unsigned)((row_)*64 + (((((s_)>>1) ^ (((row_)>>1)&3))<<4) | (((s_)&1)<<3))))

  // 4 ds_read_b64: A-frags for one (mh, ks) into dst_[4]
  #define LOADA(dst_, cbase_, mh_, ks_) do{                                      \
    const int s_ = (ks_)*4 + (lane>>4);                                          \
    _Pragma("unroll")                                                            \
    for (int f=0; f<4; f++){                                                     \
      const int row_ = wm*128 + ((mh_)*4+f)*16 + (lane&15);                      \
      dst_[f] = *(const unsigned long long*)(smem + (cbase_) + FOFF(row_, s_));  \
    }                                                                            \
  }while(0)

  // 4 ds_read_b64: B-frags (all 4 n) for one ks into dst_[4]
  #define LOADB(dst_, cbase_, ks_) do{                                           \
    const int s_ = (ks_)*4 + (lane>>4);                                          \
    _Pragma("unroll")                                                            \
    for (int g=0; g<4; g++){                                                     \
      const int row_ = wn*64 + g*16 + (lane&15);                                 \
      dst_[g] = *(const unsigned long long*)(smem + (cbase_) + 16384u            \
                                             + FOFF(row_, s_));                  \
    }                                                                            \
  }while(0)

  // 16 independent MFMA: quadrant mh x all n, one ks
  #define MFMAP(mh_, af_, bf_)                                                   \
    __builtin_amdgcn_s_setprio(1);                                               \
    _Pragma("unroll")                                                            \
    for (int f=0; f<4; f++)                                                      \
      _Pragma("unroll")                                                          \
      for (int g=0; g<4; g++)                                                    \
        acc[(mh_)*4+f][g] = __builtin_amdgcn_mfma_f32_16x16x32_fp8_fp8(          \
            (long long)af_[f], (long long)bf_[g], acc[(mh_)*4+f][g], 0, 0, 0);   \
    __builtin_amdgcn_s_setprio(0);

  STAGE_KT(0);
  aptr += 64; bptr += 64;                // -> K-tile 1 data
  __syncthreads();                       // pipeline fill (once per kernel)

  for (int kt=0; kt<TPB*NKT; kt++){      // 64 K-tile steps, continuous
    const unsigned cbase = (unsigned)(kt&1)*32768u;
    // prefetch K-tile kt+1, then counted wait: stage(kt) landed (issued one
    // full K-tile ago), stage(kt+1)'s 4 loads stay in flight.
    if (kt < TPB*NKT-1){
      STAGE_KT((kt+1)&1);
      // advance pointers to tile kt+2's data
      const bool wrap = ((kt+1)&7) == 7;
      aptr += wrap ? -(7*64) : 64;
      bptr += wrap ? (16*(size_t)BN*D_DIM - 7*64) : 64;
      asm volatile("s_waitcnt vmcnt(4)" ::: "memory");
    } else {
      asm volatile("s_waitcnt vmcnt(0)" ::: "memory");
    }
    __builtin_amdgcn_s_barrier();        // publish buffer kt (vmcnt per-wave)

    // intra-tile: compiler-scheduled software pipeline
    unsigned long long a0[4], a1[4], bf0[4], bf1[4];
    LOADB(bf0, cbase, 0);
    LOADA(a0, cbase, 0, 0);
    MFMAP(0, a0, bf0);
    LOADA(a1, cbase, 1, 0);
    MFMAP(1, a1, bf0);
    LOADB(bf1, cbase, 1);
    LOADA(a0, cbase, 0, 1);
    MFMAP(0, a0, bf1);
    LOADA(a1, cbase, 1, 1);
    MFMAP(1, a1, bf1);
    __builtin_amdgcn_s_barrier();        // end-of-tile: buf kt free to restage

    // ---- per-nt-tile epilogue: threshold filter + rare atomic append ----
    if ((kt & (NKT-1)) == NKT-1){
      const int ntc  = nt0 + 16*(kt >> 3);
      const int colb = ntc*BN + wn*64 + (lane&15);
      const int rowb = mt*BM + wm*128 + ((lane>>4)<<2);
      #pragma unroll
      for (int mf=0; mf<8; mf++){
        #pragma unroll
        for (int nf=0; nf<4; nf++){
          f32x4 a = acc[mf][nf];
          float mx = fmaxf(fmaxf(a[0],a[1]), fmaxf(a[2],a[3]));
          if (mx > TAU_S){
            int colg  = colb + nf*16;
            int rowg0 = rowb + mf*16;
            #pragma unroll
            for (int jj=0; jj<4; jj++){
              if (a[jj] > TAU_S){
                int rowg = rowg0 + jj;
                int pos = atomicAdd(cnt + rowg, 1);
                if (pos < CAP)
                  cand[(size_t)rowg*CAP + pos] = make_float2(a[jj], __int_as_float(colg));
              }
            }
          }
          acc[mf][nf] = zero4;           // reset for next nt-tile
        }
      }
    }
  }
  #undef STAGE_KT
  #undef FOFF
  #undef LOADA
  #undef LOADB
  #undef MFMAP
}

// One block per query: exact rank-select top-64 from candidate list ->
// exact fp64 rescore -> exact top-8 (ties: lower index) -> outputs.
__global__ __launch_bounds__(256) void merge_rescore(const int* __restrict__ cnt,
                                                     const float2* __restrict__ cand,
                                                     const float* __restrict__ q,
                                                     const float* __restrict__ keys,
                                                     const float* __restrict__ values,
                                                     float* __restrict__ out){
  const int qi = blockIdx.x, tid = threadIdx.x;
  const int lane = tid & 63, w = tid >> 6;
  __shared__ __align__(16) float qrow[D_DIM];
  __shared__ __align__(16) float2 ent[CAP];
  __shared__ int    widx[RWIN];
  __shared__ double dsc[RWIN];
  __shared__ double wq[4];
  __shared__ int    fidx[8];
  __shared__ double fsc[8];

  // stage q row + fp64 ||q||^2
  float2 qv = ((const float2*)(q + (size_t)qi*D_DIM))[tid];
  qrow[tid*2] = qv.x; qrow[tid*2+1] = qv.y;
  double pq = (double)qv.x*qv.x + (double)qv.y*qv.y;
  #pragma unroll
  for (int off=32; off>0; off>>=1) pq += __shfl_xor(pq, off);
  if (lane == 0) wq[w] = pq;

  const int n = min(cnt[qi], CAP);
  for (int i = tid; i < n; i += 256) ent[i] = cand[(size_t)qi*CAP + i];
  if (tid < RWIN) widx[tid] = -1;
  __syncthreads();
  double qq = wq[0]+wq[1]+wq[2]+wq[3];

  // exact rank-select: rank under (score desc, col asc); ranks are unique.
  for (int e = tid; e < n; e += 256){
    float se = ent[e].x; int ce = __float_as_int(ent[e].y);
    int rank = 0;
    for (int jx = 0; jx < n; jx++){
      float sj = ent[jx].x; int cj = __float_as_int(ent[jx].y);
      rank += (sj > se) || (sj == se && cj < ce);
    }
    if (rank < RWIN) widx[rank] = ce;
  }
  __syncthreads();

  // exact fp64 rescore: 4 threads per candidate (64 x 4 = 256)
  const int g = tid >> 2, sub = tid & 3;
  const int ki = widx[g];
  const int kis = (ki < 0) ? 0 : ki;
  const float4* kr4 = (const float4*)(keys + (size_t)kis*D_DIM);
  const float4* qr4 = (const float4*)qrow;
  double da = 0.0, dk = 0.0;
  for (int i=0;i<32;i++){
    float4 kv  = kr4[sub*32+i];
    float4 qv4 = qr4[sub*32+i];
    da += (double)qv4.x*kv.x + (double)qv4.y*kv.y + (double)qv4.z*kv.z + (double)qv4.w*kv.w;
    dk += (double)kv.x*kv.x + (double)kv.y*kv.y + (double)kv.z*kv.z + (double)kv.w*kv.w;
  }
  da += __shfl_down(da, 2, 4); da += __shfl_down(da, 1, 4);
  dk += __shfl_down(dk, 2, 4); dk += __shfl_down(dk, 1, 4);
  if (sub == 0){
    double nq = fmax(sqrt(qq), 1e-12);
    double nk = fmax(sqrt(dk), 1e-12);
    dsc[g] = (ki < 0) ? -1e300 : da/(nq*nk);
  }
  __syncthreads();

  if (tid == 0){
    for (int s=0; s<8; s++){
      double bs = -1e301; int bi = 0; int bx = 0x7fffffff;
      for (int c=0; c<RWIN; c++){
        double v = dsc[c]; int ix = widx[c];
        if (v > bs || (v == bs && ix >= 0 && ix < bx)){ bs = v; bi = c; bx = ix; }
      }
      fsc[s] = bs; fidx[s] = (bx == 0x7fffffff) ? 0 : bx;
      dsc[bi] = -1e302;   // remove
    }
  }
  __syncthreads();

  float* out_sc  = out + (size_t)B_Q*K_TOP*V_DIM;
  float* out_idx = out_sc + (size_t)B_Q*K_TOP;
  if (tid < 8){
    out_sc [qi*K_TOP + tid] = (float)fsc[tid];
    out_idx[qi*K_TOP + tid] = (float)fidx[tid];
  }
  #pragma unroll
  for (int s=0; s<8; s++){
    const float2* vr = (const float2*)(values + (size_t)fidx[s]*V_DIM);
    float2* orow = (float2*)(out + ((size_t)qi*K_TOP + s)*V_DIM);
    orow[tid] = vr[tid];
  }
}

extern "C" void kernel_launch(void* const* d_in, const int* in_sizes, int n_in,
                              void* d_out, int out_size, void* d_ws, size_t ws_size,
                              hipStream_t stream){
  const float* q      = (const float*)d_in[0];
  const float* keys   = (const float*)d_in[1];
  const float* values = (const float*)d_in[2];
  unsigned char* ws = (unsigned char*)d_ws;
  uint8_t* qn = (uint8_t*)ws;                                   // 512 KB (fp8)
  uint8_t* kn = qn + (size_t)B_Q*D_DIM;                         // 128 MB (fp8)
  int*    cnt  = (int*)(ws + (size_t)(B_Q + C_K)*D_DIM);        // 4 KB
  float2* cand = (float2*)(ws + (size_t)(B_Q + C_K)*D_DIM + 8192); // 16 MB
  float* out = (float*)d_out;

  hipFuncSetAttribute((const void*)gemm_topk,
                      hipFuncAttributeMaxDynamicSharedMemorySize, 65536);

  nrm_rows<<<dim3(B_Q/4), dim3(256), 0, stream>>>(q, qn, B_Q, cnt, B_Q);
  nrm_rows<<<dim3(C_K/4), dim3(256), 0, stream>>>(keys, kn, C_K, nullptr, 0);
  gemm_topk<<<dim3(512), dim3(512), 65536, stream>>>(qn, kn, cnt, cand);
  merge_rescore<<<dim3(B_Q), dim3(256), 0, stream>>>(cnt, cand, q, keys, values, out);
}

// Round 11
// 495.227 us; speedup vs baseline: 3.1537x; 3.1537x over previous
//
#include <hip/hip_runtime.h>
#include <hip/hip_bf16.h>
#include <stdint.h>

#define B_Q   1024
#define C_K   262144
#define D_DIM 512
#define V_DIM 512
#define K_TOP 8
#define BM 256
#define BN 256
#define BK 64
#define NT (C_K/BN)    /* 1024 n-tiles */
#define MT (B_Q/BM)    /* 4 m-tiles */
#define NKT (D_DIM/BK) /* 8 K-tiles per nt-tile */
#define TPB 16         /* nt-tiles per persistent block (grid 256, 1/CU) */
#define CAP 2048       /* candidate list capacity per query (E[n]~293) */
#define QS 8.0f        /* per-side fp8 pre-scale */
#define TAU_S 8.64f    /* 64 * 0.135 (z=3.05); rescore window 64 -> 13-sigma margin */
#define RWIN 64        /* exact-rescore window */

typedef float f32x4 __attribute__((ext_vector_type(4)));
typedef __attribute__((address_space(3))) unsigned char lds_uchar;
typedef __attribute__((address_space(1))) const unsigned char gbl_uchar;

// One wave per row: L2-normalize (fp32 norm), scale by QS, emit fp8 e4m3.
// Block 0 additionally zeroes the candidate counters (when cnt != nullptr).
__global__ __launch_bounds__(256) void nrm_rows(const float* __restrict__ in,
                                                uint8_t* __restrict__ out,
                                                int nrows, int* cnt, int ncnt){
  if (cnt != nullptr && blockIdx.x == 0){
    for (int i = threadIdx.x; i < ncnt; i += 256) cnt[i] = 0;
  }
  int row  = blockIdx.x*4 + (threadIdx.x>>6);
  int lane = threadIdx.x & 63;
  if (row >= nrows) return;
  const float4* r4 = (const float4*)(in + (size_t)row*D_DIM);
  float4 a = r4[lane*2], b = r4[lane*2+1];
  float ss = a.x*a.x+a.y*a.y+a.z*a.z+a.w*a.w
           + b.x*b.x+b.y*b.y+b.z*b.z+b.w*b.w;
  #pragma unroll
  for (int off=32; off>0; off>>=1) ss += __shfl_xor(ss, off);
  float rn = QS / fmaxf(sqrtf(ss), 1e-12f);
  int w0 = __builtin_amdgcn_cvt_pk_fp8_f32(a.x*rn, a.y*rn, 0,  false);
  w0     = __builtin_amdgcn_cvt_pk_fp8_f32(a.z*rn, a.w*rn, w0, true);
  int w1 = __builtin_amdgcn_cvt_pk_fp8_f32(b.x*rn, b.y*rn, 0,  false);
  w1     = __builtin_amdgcn_cvt_pk_fp8_f32(b.z*rn, b.w*rn, w1, true);
  ((uint2*)(out + (size_t)row*D_DIM))[lane] = make_uint2((unsigned)w0, (unsigned)w1);
}

// PERSISTENT 256x256 fp8 MFMA GEMM (scores scaled by 64): grid=256 (1
// block/CU). Loop head (R7/R8-proven): STAGE(kt+1) -> vmcnt(4) [STAGE(kt)'s
// loads now OLDER than the 4 newest => landed] -> publish s_barrier. NOTE
// (R10 bug): vmcnt(N) proves nothing about the newest N ops — never "publish"
// right after issuing the loads you're publishing. Inside the tile: m201-style
// 4-phase schedule {reads issue -> s_barrier -> lgkmcnt(0)+sched_barrier ->
// setprio MFMA x16}; end-of-tile barrier keeps restage-vs-read hazard closed.
// Swizzle: 16B unit u' = u ^ ((row>>1)&3); with natural bit6=row&1, 16
// consecutive rows -> 8 regions x 2-way (free). Linear LDS dest +
// inverse-swizzled global source (global_load_lds-compatible).
// Epilogue per nt-tile = threshold filter + rare atomic append.
__global__ __launch_bounds__(512) void gemm_topk(const uint8_t* __restrict__ qn,
                                                 const uint8_t* __restrict__ kn,
                                                 int* __restrict__ cnt,
                                                 float2* __restrict__ cand){
  extern __shared__ __align__(16) unsigned char smem[];   // 65536 bytes

  const int tid  = threadIdx.x;
  const int lane = tid & 63;
  const int w    = tid >> 6;           // 0..7
  const int wm = w >> 2, wn = w & 3;   // 2 x 4 wave grid

  const unsigned bid = blockIdx.x;     // 0..255
  const int xcd  = bid & 7;
  const int s    = bid >> 3;           // 0..31
  const int mt   = s & 3;
  const int nt0  = xcd*128 + (s >> 2); // tile tt -> nt = nt0 + 8*tt

  f32x4 zero4 = {0.f,0.f,0.f,0.f};
  f32x4 acc[8][4];
  #pragma unroll
  for (int a=0;a<8;a++)
    #pragma unroll
    for (int b=0;b<4;b++) acc[a][b] = zero4;

  const uint8_t* ab  = qn + (size_t)mt*BM*D_DIM;
  const uint8_t* bb0 = kn + (size_t)nt0*BN*D_DIM;

  // staging map: thread t covers 16B units {t, t+512} of A and of B.
  // unit n -> row n>>2, dest-unit n&3; source unit = (n&3) ^ ((row>>1)&3).
  const int srow = tid >> 2;                                  // 0..127
  const unsigned ssw = (unsigned)(((tid & 3) ^ ((srow >> 1) & 3)) << 4);
  const uint8_t* aptr = ab  + (size_t)srow*D_DIM + ssw;       // += 64/K-tile
  const uint8_t* bptr = bb0 + (size_t)srow*D_DIM + ssw;
  const unsigned dst0 = (unsigned)tid*16u;

  #define STAGE_KT(buf_) do{                                                    \
    const unsigned cb_ = (unsigned)(buf_)*32768u;                                \
    __builtin_amdgcn_global_load_lds((gbl_uchar*)(aptr),                         \
        (lds_uchar*)(smem + cb_ + dst0), 16, 0, 0);                              \
    __builtin_amdgcn_global_load_lds((gbl_uchar*)(aptr + 128*D_DIM),             \
        (lds_uchar*)(smem + cb_ + 8192u + dst0), 16, 0, 0);                      \
    __builtin_amdgcn_global_load_lds((gbl_uchar*)(bptr),                         \
        (lds_uchar*)(smem + cb_ + 16384u + dst0), 16, 0, 0);                     \
    __builtin_amdgcn_global_load_lds((gbl_uchar*)(bptr + 128*D_DIM),             \
        (lds_uchar*)(smem + cb_ + 24576u + dst0), 16, 0, 0);                     \
  }while(0)

  // frag byte offset for (row_, slot s_): s_ = ks*4 + (lane>>4), 8B granule
  #define FOFF(row_, s_) \
    ((unsigned)((row_)*64 + (((((s_)>>1) ^ (((row_)>>1)&3))<<4) | (((s_)&1)<<3))))

  // 4 ds_read_b64: A-frags for one (mh, ks) into dst_[4]
  #define LOADA(dst_, cbase_, mh_, ks_) do{                                      \
    const int s_ = (ks_)*4 + (lane>>4);                                          \
    _Pragma("unroll")                                                            \
    for (int f=0; f<4; f++){                                                     \
      const int row_ = wm*128 + ((mh_)*4+f)*16 + (lane&15);                      \
      dst_[f] = *(const unsigned long long*)(smem + (cbase_) + FOFF(row_, s_));  \
    }                                                                            \
  }while(0)

  // 4 ds_read_b64: B-frags (all 4 n) for one ks into dst_[4]
  #define LOADB(dst_, cbase_, ks_) do{                                           \
    const int s_ = (ks_)*4 + (lane>>4);                                          \
    _Pragma("unroll")                                                            \
    for (int g=0; g<4; g++){                                                     \
      const int row_ = wn*64 + g*16 + (lane&15);                                 \
      dst_[g] = *(const unsigned long long*)(smem + (cbase_) + 16384u            \
                                             + FOFF(row_, s_));                  \
    }                                                                            \
  }while(0)

  // 16 independent MFMA: quadrant mh x all n, one ks
  #define MFMAP(mh_, af_, bf_)                                                   \
    __builtin_amdgcn_s_setprio(1);                                               \
    _Pragma("unroll")                                                            \
    for (int f=0; f<4; f++)                                                      \
      _Pragma("unroll")                                                          \
      for (int g=0; g<4; g++)                                                    \
        acc[(mh_)*4+f][g] = __builtin_amdgcn_mfma_f32_16x16x32_fp8_fp8(          \
            (long long)af_[f], (long long)bf_[g], acc[(mh_)*4+f][g], 0, 0, 0);   \
    __builtin_amdgcn_s_setprio(0);

  // phase boundary: barrier, then wait own ds_reads, then pin (rule #18)
  #define PHASE_SYNC                                                             \
    __builtin_amdgcn_s_barrier();                                                \
    asm volatile("s_waitcnt lgkmcnt(0)" ::: "memory");                           \
    __builtin_amdgcn_sched_barrier(0);

  STAGE_KT(0);
  aptr += 64; bptr += 64;                // -> K-tile 1 data
  __syncthreads();                       // prologue

  for (int kt=0; kt<TPB*NKT; kt++){      // 128 K-tile steps, continuous
    const unsigned cbase = (unsigned)(kt&1)*32768u;
    unsigned long long a0[4], a1[4], bf0[4], bf1[4];

    // loop head (proven): issue STAGE(kt+1), then counted wait — STAGE(kt)'s
    // loads are now older than the 4 newest => landed. Then publish.
    if (kt < TPB*NKT-1){
      STAGE_KT((kt+1)&1);
      const bool wrap = ((kt+1)&7) == 7;   // advance to kt+2's data
      aptr += wrap ? -(7*64) : 64;
      bptr += wrap ? (8*(size_t)BN*D_DIM - 7*64) : 64;
      asm volatile("s_waitcnt vmcnt(4)" ::: "memory");
    } else {
      asm volatile("s_waitcnt vmcnt(0)" ::: "memory");
    }
    __builtin_amdgcn_sched_barrier(0);
    __builtin_amdgcn_s_barrier();        // publish buffer kt (vmcnt per-wave)

    // phase 0: reads {B(ks0), A(mh0,ks0)}
    LOADB(bf0, cbase, 0);
    LOADA(a0, cbase, 0, 0);
    PHASE_SYNC
    MFMAP(0, a0, bf0);
    // phase 1: reads A(mh1,ks0); B(ks0) register-held
    LOADA(a1, cbase, 1, 0);
    PHASE_SYNC
    MFMAP(1, a1, bf0);
    // phase 2: reads {B(ks1), A(mh0,ks1)}
    LOADB(bf1, cbase, 1);
    LOADA(a0, cbase, 0, 1);
    PHASE_SYNC
    MFMAP(0, a0, bf1);
    // phase 3: reads A(mh1,ks1)
    LOADA(a1, cbase, 1, 1);
    PHASE_SYNC
    MFMAP(1, a1, bf1);
    __builtin_amdgcn_s_barrier();        // end-of-tile: buf kt free to restage

    // ---- per-nt-tile epilogue: threshold filter + rare atomic append ----
    if ((kt & (NKT-1)) == NKT-1){
      const int ntc  = nt0 + 8*(kt >> 3);
      const int colb = ntc*BN + wn*64 + (lane&15);
      const int rowb = mt*BM + wm*128 + ((lane>>4)<<2);
      #pragma unroll
      for (int mf=0; mf<8; mf++){
        #pragma unroll
        for (int nf=0; nf<4; nf++){
          f32x4 a = acc[mf][nf];
          float mx = fmaxf(fmaxf(a[0],a[1]), fmaxf(a[2],a[3]));
          if (mx > TAU_S){
            int colg  = colb + nf*16;
            int rowg0 = rowb + mf*16;
            #pragma unroll
            for (int jj=0; jj<4; jj++){
              if (a[jj] > TAU_S){
                int rowg = rowg0 + jj;
                int pos = atomicAdd(cnt + rowg, 1);
                if (pos < CAP)
                  cand[(size_t)rowg*CAP + pos] = make_float2(a[jj], __int_as_float(colg));
              }
            }
          }
          acc[mf][nf] = zero4;           // reset for next nt-tile
        }
      }
    }
  }
  #undef STAGE_KT
  #undef FOFF
  #undef LOADA
  #undef LOADB
  #undef MFMAP
  #undef PHASE_SYNC
}

// One block per query: exact rank-select top-64 from candidate list ->
// exact fp64 rescore -> exact top-8 (ties: lower index) -> outputs.
__global__ __launch_bounds__(256) void merge_rescore(const int* __restrict__ cnt,
                                                     const float2* __restrict__ cand,
                                                     const float* __restrict__ q,
                                                     const float* __restrict__ keys,
                                                     const float* __restrict__ values,
                                                     float* __restrict__ out){
  const int qi = blockIdx.x, tid = threadIdx.x;
  const int lane = tid & 63, w = tid >> 6;
  __shared__ __align__(16) float qrow[D_DIM];
  __shared__ __align__(16) float2 ent[CAP];
  __shared__ int    widx[RWIN];
  __shared__ double dsc[RWIN];
  __shared__ double wq[4];
  __shared__ int    fidx[8];
  __shared__ double fsc[8];

  // stage q row + fp64 ||q||^2
  float2 qv = ((const float2*)(q + (size_t)qi*D_DIM))[tid];
  qrow[tid*2] = qv.x; qrow[tid*2+1] = qv.y;
  double pq = (double)qv.x*qv.x + (double)qv.y*qv.y;
  #pragma unroll
  for (int off=32; off>0; off>>=1) pq += __shfl_xor(pq, off);
  if (lane == 0) wq[w] = pq;

  const int n = min(cnt[qi], CAP);
  for (int i = tid; i < n; i += 256) ent[i] = cand[(size_t)qi*CAP + i];
  if (tid < RWIN) widx[tid] = -1;
  __syncthreads();
  double qq = wq[0]+wq[1]+wq[2]+wq[3];

  // exact rank-select: rank under (score desc, col asc); ranks are unique.
  for (int e = tid; e < n; e += 256){
    float se = ent[e].x; int ce = __float_as_int(ent[e].y);
    int rank = 0;
    for (int jx = 0; jx < n; jx++){
      float sj = ent[jx].x; int cj = __float_as_int(ent[jx].y);
      rank += (sj > se) || (sj == se && cj < ce);
    }
    if (rank < RWIN) widx[rank] = ce;
  }
  __syncthreads();

  // exact fp64 rescore: 4 threads per candidate (64 x 4 = 256)
  const int g = tid >> 2, sub = tid & 3;
  const int ki = widx[g];
  const int kis = (ki < 0) ? 0 : ki;
  const float4* kr4 = (const float4*)(keys + (size_t)kis*D_DIM);
  const float4* qr4 = (const float4*)qrow;
  double da = 0.0, dk = 0.0;
  for (int i=0;i<32;i++){
    float4 kv  = kr4[sub*32+i];
    float4 qv4 = qr4[sub*32+i];
    da += (double)qv4.x*kv.x + (double)qv4.y*kv.y + (double)qv4.z*kv.z + (double)qv4.w*kv.w;
    dk += (double)kv.x*kv.x + (double)kv.y*kv.y + (double)kv.z*kv.z + (double)kv.w*kv.w;
  }
  da += __shfl_down(da, 2, 4); da += __shfl_down(da, 1, 4);
  dk += __shfl_down(dk, 2, 4); dk += __shfl_down(dk, 1, 4);
  if (sub == 0){
    double nq = fmax(sqrt(qq), 1e-12);
    double nk = fmax(sqrt(dk), 1e-12);
    dsc[g] = (ki < 0) ? -1e300 : da/(nq*nk);
  }
  __syncthreads();

  if (tid == 0){
    for (int s=0; s<8; s++){
      double bs = -1e301; int bi = 0; int bx = 0x7fffffff;
      for (int c=0; c<RWIN; c++){
        double v = dsc[c]; int ix = widx[c];
        if (v > bs || (v == bs && ix >= 0 && ix < bx)){ bs = v; bi = c; bx = ix; }
      }
      fsc[s] = bs; fidx[s] = (bx == 0x7fffffff) ? 0 : bx;
      dsc[bi] = -1e302;   // remove
    }
  }
  __syncthreads();

  float* out_sc  = out + (size_t)B_Q*K_TOP*V_DIM;
  float* out_idx = out_sc + (size_t)B_Q*K_TOP;
  if (tid < 8){
    out_sc [qi*K_TOP + tid] = (float)fsc[tid];
    out_idx[qi*K_TOP + tid] = (float)fidx[tid];
  }
  #pragma unroll
  for (int s=0; s<8; s++){
    const float2* vr = (const float2*)(values + (size_t)fidx[s]*V_DIM);
    float2* orow = (float2*)(out + ((size_t)qi*K_TOP + s)*V_DIM);
    orow[tid] = vr[tid];
  }
}

extern "C" void kernel_launch(void* const* d_in, const int* in_sizes, int n_in,
                              void* d_out, int out_size, void* d_ws, size_t ws_size,
                              hipStream_t stream){
  const float* q      = (const float*)d_in[0];
  const float* keys   = (const float*)d_in[1];
  const float* values = (const float*)d_in[2];
  unsigned char* ws = (unsigned char*)d_ws;
  uint8_t* qn = (uint8_t*)ws;                                   // 512 KB (fp8)
  uint8_t* kn = qn + (size_t)B_Q*D_DIM;                         // 128 MB (fp8)
  int*    cnt  = (int*)(ws + (size_t)(B_Q + C_K)*D_DIM);        // 4 KB
  float2* cand = (float2*)(ws + (size_t)(B_Q + C_K)*D_DIM + 8192); // 16 MB
  float* out = (float*)d_out;

  hipFuncSetAttribute((const void*)gemm_topk,
                      hipFuncAttributeMaxDynamicSharedMemorySize, 65536);

  nrm_rows<<<dim3(B_Q/4), dim3(256), 0, stream>>>(q, qn, B_Q, cnt, B_Q);
  nrm_rows<<<dim3(C_K/4), dim3(256), 0, stream>>>(keys, kn, C_K, nullptr, 0);
  gemm_topk<<<dim3(256), dim3(512), 65536, stream>>>(qn, kn, cnt, cand);
  merge_rescore<<<dim3(B_Q), dim3(256), 0, stream>>>(cnt, cand, q, keys, values, out);
}

// Round 12
// 472.362 us; speedup vs baseline: 3.3063x; 1.0484x over previous
//
#include <hip/hip_runtime.h>
#include <hip/hip_bf16.h>
#include <stdint.h>

#define B_Q   1024
#define C_K   262144
#define D_DIM 512
#define V_DIM 512
#define K_TOP 8
#define BM 128
#define BN 128
#define BK 64
#define NT (C_K/BN)    /* 2048 n-tiles */
#define MT (B_Q/BM)    /* 8 m-tiles */
#define NKT (D_DIM/BK) /* 8 K-tiles per nt-tile */
#define TPB 32         /* nt-tiles per persistent block (grid 512, 2/CU) */
#define CAP 2048       /* candidate list capacity per query (E[n]~293) */
#define QS 8.0f        /* per-side fp8 pre-scale */
#define TAU_S 8.64f    /* 64 * 0.135 (z=3.05); rescore window 64 -> 13-sigma margin */
#define RWIN 64        /* exact-rescore window */

typedef float f32x4 __attribute__((ext_vector_type(4)));
typedef __attribute__((address_space(3))) unsigned char lds_uchar;
typedef __attribute__((address_space(1))) const unsigned char gbl_uchar;

// One wave per row: L2-normalize (fp32 norm), scale by QS, emit fp8 e4m3.
// Block 0 additionally zeroes the candidate counters (when cnt != nullptr).
__global__ __launch_bounds__(256) void nrm_rows(const float* __restrict__ in,
                                                uint8_t* __restrict__ out,
                                                int nrows, int* cnt, int ncnt){
  if (cnt != nullptr && blockIdx.x == 0){
    for (int i = threadIdx.x; i < ncnt; i += 256) cnt[i] = 0;
  }
  int row  = blockIdx.x*4 + (threadIdx.x>>6);
  int lane = threadIdx.x & 63;
  if (row >= nrows) return;
  const float4* r4 = (const float4*)(in + (size_t)row*D_DIM);
  float4 a = r4[lane*2], b = r4[lane*2+1];
  float ss = a.x*a.x+a.y*a.y+a.z*a.z+a.w*a.w
           + b.x*b.x+b.y*b.y+b.z*b.z+b.w*b.w;
  #pragma unroll
  for (int off=32; off>0; off>>=1) ss += __shfl_xor(ss, off);
  float rn = QS / fmaxf(sqrtf(ss), 1e-12f);
  int w0 = __builtin_amdgcn_cvt_pk_fp8_f32(a.x*rn, a.y*rn, 0,  false);
  w0     = __builtin_amdgcn_cvt_pk_fp8_f32(a.z*rn, a.w*rn, w0, true);
  int w1 = __builtin_amdgcn_cvt_pk_fp8_f32(b.x*rn, b.y*rn, 0,  false);
  w1     = __builtin_amdgcn_cvt_pk_fp8_f32(b.z*rn, b.w*rn, w1, true);
  ((uint2*)(out + (size_t)row*D_DIM))[lane] = make_uint2((unsigned)w0, (unsigned)w1);
}

// PERSISTENT 128x128 fp8 MFMA GEMM (scores scaled by 64): grid=512 = 2
// blocks/CU (the R8-R11 lesson: 256^2 acc alone = 128 unified regs -> 1
// block/CU, all stalls exposed; this tile: acc[4][2]=32 AGPR + ~80 VGPR
// fits 4 waves/SIMD so the co-resident block's MFMA covers barriers).
// 8 waves (2Mx4N), each owns 64x32. LDS 2 x 16KB double buffer.
// Loop head (R7/R8/R11-proven): STAGE(kt+1) -> vmcnt(2) [STAGE(kt)'s loads
// now OLDER than the 2 newest => landed] -> publish s_barrier. Single phase:
// 12 ds_read_b64 -> s_barrier -> lgkmcnt(0)+sched_barrier -> setprio MFMA
// x16 -> end barrier (restage hazard). Swizzle: 16B unit u' = u^((row>>1)&3),
// linear LDS dest + inverse-swizzled global source.
// Epilogue per nt-tile = threshold filter + rare atomic append.
__global__ __launch_bounds__(512, 4) void gemm_topk(const uint8_t* __restrict__ qn,
                                                    const uint8_t* __restrict__ kn,
                                                    int* __restrict__ cnt,
                                                    float2* __restrict__ cand){
  extern __shared__ __align__(16) unsigned char smem[];   // 32768 bytes

  const int tid  = threadIdx.x;
  const int lane = tid & 63;
  const int w    = tid >> 6;           // 0..7
  const int wm = w >> 2, wn = w & 3;   // 2 x 4 wave grid: 128 rows x 128 cols

  const unsigned bid = blockIdx.x;     // 0..511
  const int xcd  = bid & 7;
  const int s    = bid >> 3;           // 0..63
  const int mt   = s & 7;              // 8 m-tiles
  const int nt0  = xcd*256 + (s >> 3)*TPB;   // group walks nt0..nt0+31

  f32x4 zero4 = {0.f,0.f,0.f,0.f};
  f32x4 acc[4][2];
  #pragma unroll
  for (int a=0;a<4;a++)
    #pragma unroll
    for (int b=0;b<2;b++) acc[a][b] = zero4;

  const uint8_t* ab  = qn + (size_t)mt*BM*D_DIM;
  const uint8_t* bb0 = kn + (size_t)nt0*BN*D_DIM;

  // staging map: thread t covers 16B unit t of A and unit t of B (512 each).
  // unit n -> row n>>2, dest-unit n&3; source unit = (n&3) ^ ((row>>1)&3).
  const int srow = tid >> 2;                                  // 0..127
  const unsigned ssw = (unsigned)(((tid & 3) ^ ((srow >> 1) & 3)) << 4);
  const uint8_t* aptr = ab  + (size_t)srow*D_DIM + ssw;       // += 64/K-tile
  const uint8_t* bptr = bb0 + (size_t)srow*D_DIM + ssw;
  const unsigned dst0 = (unsigned)tid*16u;

  #define STAGE_KT(buf_) do{                                                    \
    const unsigned cb_ = (unsigned)(buf_)*16384u;                                \
    __builtin_amdgcn_global_load_lds((gbl_uchar*)(aptr),                         \
        (lds_uchar*)(smem + cb_ + dst0), 16, 0, 0);                              \
    __builtin_amdgcn_global_load_lds((gbl_uchar*)(bptr),                         \
        (lds_uchar*)(smem + cb_ + 8192u + dst0), 16, 0, 0);                      \
  }while(0)

  // frag byte offset for (row_, slot s_): s_ = ks*4 + (lane>>4), 8B granule
  #define FOFF(row_, s_) \
    ((unsigned)((row_)*64 + (((((s_)>>1) ^ (((row_)>>1)&3))<<4) | (((s_)&1)<<3))))

  // 4 ds_read_b64: A-frags (all 4 m) for one ks into dst_[4]
  #define LOADA(dst_, cbase_, ks_) do{                                           \
    const int s_ = (ks_)*4 + (lane>>4);                                          \
    _Pragma("unroll")                                                            \
    for (int f=0; f<4; f++){                                                     \
      const int row_ = wm*64 + f*16 + (lane&15);                                 \
      dst_[f] = *(const unsigned long long*)(smem + (cbase_) + FOFF(row_, s_));  \
    }                                                                            \
  }while(0)

  // 2 ds_read_b64: B-frags (both n) for one ks into dst_[2]
  #define LOADB(dst_, cbase_, ks_) do{                                           \
    const int s_ = (ks_)*4 + (lane>>4);                                          \
    _Pragma("unroll")                                                            \
    for (int g=0; g<2; g++){                                                     \
      const int row_ = wn*32 + g*16 + (lane&15);                                 \
      dst_[g] = *(const unsigned long long*)(smem + (cbase_) + 8192u             \
                                             + FOFF(row_, s_));                  \
    }                                                                            \
  }while(0)

  // 8 independent MFMA: all 4m x 2n, one ks
  #define MFMAP(af_, bf_)                                                        \
    _Pragma("unroll")                                                            \
    for (int f=0; f<4; f++)                                                      \
      _Pragma("unroll")                                                          \
      for (int g=0; g<2; g++)                                                    \
        acc[f][g] = __builtin_amdgcn_mfma_f32_16x16x32_fp8_fp8(                  \
            (long long)af_[f], (long long)bf_[g], acc[f][g], 0, 0, 0);

  STAGE_KT(0);
  aptr += 64; bptr += 64;                // -> K-tile 1 data
  __syncthreads();                       // prologue

  for (int kt=0; kt<TPB*NKT; kt++){      // 256 K-tile steps, continuous
    const unsigned cbase = (unsigned)(kt&1)*16384u;
    unsigned long long a0[4], a1[4], b0[2], b1[2];

    // loop head (proven): issue STAGE(kt+1), then counted wait — STAGE(kt)'s
    // loads are now older than the 2 newest => landed. Then publish.
    if (kt < TPB*NKT-1){
      STAGE_KT((kt+1)&1);
      const bool wrap = ((kt+1)&7) == 7;   // advance to kt+2's data
      aptr += wrap ? -(7*64) : 64;
      bptr += wrap ? ((size_t)BN*D_DIM - 7*64) : 64;
      asm volatile("s_waitcnt vmcnt(2)" ::: "memory");
    } else {
      asm volatile("s_waitcnt vmcnt(0)" ::: "memory");
    }
    __builtin_amdgcn_sched_barrier(0);
    __builtin_amdgcn_s_barrier();        // publish buffer kt (vmcnt per-wave)

    // single phase: 12 reads -> sync -> 16 MFMA
    LOADB(b0, cbase, 0);
    LOADB(b1, cbase, 1);
    LOADA(a0, cbase, 0);
    LOADA(a1, cbase, 1);
    __builtin_amdgcn_s_barrier();
    asm volatile("s_waitcnt lgkmcnt(0)" ::: "memory");
    __builtin_amdgcn_sched_barrier(0);
    __builtin_amdgcn_s_setprio(1);
    MFMAP(a0, b0);
    MFMAP(a1, b1);
    __builtin_amdgcn_s_setprio(0);
    __builtin_amdgcn_s_barrier();        // end-of-tile: buf kt free to restage

    // ---- per-nt-tile epilogue: threshold filter + rare atomic append ----
    if ((kt & (NKT-1)) == NKT-1){
      const int ntc  = nt0 + (kt >> 3);
      const int colb = ntc*BN + wn*32 + (lane&15);
      const int rowb = mt*BM + wm*64 + ((lane>>4)<<2);
      #pragma unroll
      for (int mf=0; mf<4; mf++){
        #pragma unroll
        for (int nf=0; nf<2; nf++){
          f32x4 a = acc[mf][nf];
          float mx = fmaxf(fmaxf(a[0],a[1]), fmaxf(a[2],a[3]));
          if (mx > TAU_S){
            int colg  = colb + nf*16;
            int rowg0 = rowb + mf*16;
            #pragma unroll
            for (int jj=0; jj<4; jj++){
              if (a[jj] > TAU_S){
                int rowg = rowg0 + jj;
                int pos = atomicAdd(cnt + rowg, 1);
                if (pos < CAP)
                  cand[(size_t)rowg*CAP + pos] = make_float2(a[jj], __int_as_float(colg));
              }
            }
          }
          acc[mf][nf] = zero4;           // reset for next nt-tile
        }
      }
    }
  }
  #undef STAGE_KT
  #undef FOFF
  #undef LOADA
  #undef LOADB
  #undef MFMAP
}

// One block per query: exact rank-select top-64 from candidate list ->
// exact fp64 rescore -> exact top-8 (ties: lower index) -> outputs.
__global__ __launch_bounds__(256) void merge_rescore(const int* __restrict__ cnt,
                                                     const float2* __restrict__ cand,
                                                     const float* __restrict__ q,
                                                     const float* __restrict__ keys,
                                                     const float* __restrict__ values,
                                                     float* __restrict__ out){
  const int qi = blockIdx.x, tid = threadIdx.x;
  const int lane = tid & 63, w = tid >> 6;
  __shared__ __align__(16) float qrow[D_DIM];
  __shared__ __align__(16) float2 ent[CAP];
  __shared__ int    widx[RWIN];
  __shared__ double dsc[RWIN];
  __shared__ double wq[4];
  __shared__ int    fidx[8];
  __shared__ double fsc[8];

  // stage q row + fp64 ||q||^2
  float2 qv = ((const float2*)(q + (size_t)qi*D_DIM))[tid];
  qrow[tid*2] = qv.x; qrow[tid*2+1] = qv.y;
  double pq = (double)qv.x*qv.x + (double)qv.y*qv.y;
  #pragma unroll
  for (int off=32; off>0; off>>=1) pq += __shfl_xor(pq, off);
  if (lane == 0) wq[w] = pq;

  const int n = min(cnt[qi], CAP);
  for (int i = tid; i < n; i += 256) ent[i] = cand[(size_t)qi*CAP + i];
  if (tid < RWIN) widx[tid] = -1;
  __syncthreads();
  double qq = wq[0]+wq[1]+wq[2]+wq[3];

  // exact rank-select: rank under (score desc, col asc); ranks are unique.
  for (int e = tid; e < n; e += 256){
    float se = ent[e].x; int ce = __float_as_int(ent[e].y);
    int rank = 0;
    for (int jx = 0; jx < n; jx++){
      float sj = ent[jx].x; int cj = __float_as_int(ent[jx].y);
      rank += (sj > se) || (sj == se && cj < ce);
    }
    if (rank < RWIN) widx[rank] = ce;
  }
  __syncthreads();

  // exact fp64 rescore: 4 threads per candidate (64 x 4 = 256)
  const int g = tid >> 2, sub = tid & 3;
  const int ki = widx[g];
  const int kis = (ki < 0) ? 0 : ki;
  const float4* kr4 = (const float4*)(keys + (size_t)kis*D_DIM);
  const float4* qr4 = (const float4*)qrow;
  double da = 0.0, dk = 0.0;
  for (int i=0;i<32;i++){
    float4 kv  = kr4[sub*32+i];
    float4 qv4 = qr4[sub*32+i];
    da += (double)qv4.x*kv.x + (double)qv4.y*kv.y + (double)qv4.z*kv.z + (double)qv4.w*kv.w;
    dk += (double)kv.x*kv.x + (double)kv.y*kv.y + (double)kv.z*kv.z + (double)kv.w*kv.w;
  }
  da += __shfl_down(da, 2, 4); da += __shfl_down(da, 1, 4);
  dk += __shfl_down(dk, 2, 4); dk += __shfl_down(dk, 1, 4);
  if (sub == 0){
    double nq = fmax(sqrt(qq), 1e-12);
    double nk = fmax(sqrt(dk), 1e-12);
    dsc[g] = (ki < 0) ? -1e300 : da/(nq*nk);
  }
  __syncthreads();

  if (tid == 0){
    for (int s=0; s<8; s++){
      double bs = -1e301; int bi = 0; int bx = 0x7fffffff;
      for (int c=0; c<RWIN; c++){
        double v = dsc[c]; int ix = widx[c];
        if (v > bs || (v == bs && ix >= 0 && ix < bx)){ bs = v; bi = c; bx = ix; }
      }
      fsc[s] = bs; fidx[s] = (bx == 0x7fffffff) ? 0 : bx;
      dsc[bi] = -1e302;   // remove
    }
  }
  __syncthreads();

  float* out_sc  = out + (size_t)B_Q*K_TOP*V_DIM;
  float* out_idx = out_sc + (size_t)B_Q*K_TOP;
  if (tid < 8){
    out_sc [qi*K_TOP + tid] = (float)fsc[tid];
    out_idx[qi*K_TOP + tid] = (float)fidx[tid];
  }
  #pragma unroll
  for (int s=0; s<8; s++){
    const float2* vr = (const float2*)(values + (size_t)fidx[s]*V_DIM);
    float2* orow = (float2*)(out + ((size_t)qi*K_TOP + s)*V_DIM);
    orow[tid] = vr[tid];
  }
}

extern "C" void kernel_launch(void* const* d_in, const int* in_sizes, int n_in,
                              void* d_out, int out_size, void* d_ws, size_t ws_size,
                              hipStream_t stream){
  const float* q      = (const float*)d_in[0];
  const float* keys   = (const float*)d_in[1];
  const float* values = (const float*)d_in[2];
  unsigned char* ws = (unsigned char*)d_ws;
  uint8_t* qn = (uint8_t*)ws;                                   // 512 KB (fp8)
  uint8_t* kn = qn + (size_t)B_Q*D_DIM;                         // 128 MB (fp8)
  int*    cnt  = (int*)(ws + (size_t)(B_Q + C_K)*D_DIM);        // 4 KB
  float2* cand = (float2*)(ws + (size_t)(B_Q + C_K)*D_DIM + 8192); // 16 MB
  float* out = (float*)d_out;

  hipFuncSetAttribute((const void*)gemm_topk,
                      hipFuncAttributeMaxDynamicSharedMemorySize, 65536);

  nrm_rows<<<dim3(B_Q/4), dim3(256), 0, stream>>>(q, qn, B_Q, cnt, B_Q);
  nrm_rows<<<dim3(C_K/4), dim3(256), 0, stream>>>(keys, kn, C_K, nullptr, 0);
  gemm_topk<<<dim3(512), dim3(512), 32768, stream>>>(qn, kn, cnt, cand);
  merge_rescore<<<dim3(B_Q), dim3(256), 0, stream>>>(cnt, cand, q, keys, values, out);
}